// Round 1
// baseline (3546.818 us; speedup 1.0000x reference)
//
#include <hip/hip_runtime.h>
#include <math.h>
#include <stdint.h>

#define NB    16384
#define NDVIS 1024
#define NDH   256
#define NEXP  4
#define NGENE 5000
#define NHID  1024
#define NSCVI 30
#define NPAD  10240   // padded+permuted gd2 output cols: mu 0..5119, theta 5120..10239
#define NHALF 5120

typedef unsigned short u16;
typedef short bf16x8 __attribute__((ext_vector_type(8)));
typedef float f32x4 __attribute__((ext_vector_type(4)));

__device__ __forceinline__ float gelu_f(float x) {
    return 0.5f * x * (1.0f + erff(x * 0.7071067811865476f));
}
__device__ __forceinline__ float softplus_f(float x) {
    return fmaxf(x, 0.0f) + log1pf(expf(-fabsf(x)));
}
__device__ __forceinline__ float sigmoid_f(float x) {
    return 1.0f / (1.0f + expf(-x));
}
// round-to-nearest-even fp32 -> bf16
__device__ __forceinline__ u16 bf16_rtn(float x) {
    uint32_t u = __float_as_uint(x);
    uint32_t r = (u + 0x7FFFu + ((u >> 16) & 1u)) >> 16;
    return (u16)r;
}

// ---------------------------------------------------------------- fourier
__global__ __launch_bounds__(256) void k_four(const float* __restrict__ pos,
                                              const float* __restrict__ fB,
                                              float* __restrict__ four) {
    int idx = blockIdx.x * 256 + threadIdx.x;   // b*128 + j
    int b = idx >> 7, j = idx & 127;
    float p0 = pos[b * 3 + 0], p1 = pos[b * 3 + 1], p2 = pos[b * 3 + 2];
    float xp = 6.283185307179586f * (p0 * fB[j] + p1 * fB[128 + j] + p2 * fB[256 + j]);
    four[b * NDH + j]       = sinf(xp);
    four[b * NDH + 128 + j] = cosf(xp);
}

// ---------------------------------------------------------------- z = vis@img_W + img_b + gelu(four@pos_W + pos_b)
__global__ __launch_bounds__(256) void k_z(
    const float* __restrict__ vis, const float* __restrict__ four,
    const float* __restrict__ img_W, const float* __restrict__ img_b,
    const float* __restrict__ pos_W, const float* __restrict__ pos_b,
    float* __restrict__ z)
{
    __shared__ __align__(16) float A_s[64][33];
    __shared__ __align__(16) float B_s[32][64];
    const int tid = threadIdx.x;
    const int tx4 = (tid & 15) * 4;
    const int ty4 = (tid >> 4) * 4;
    const int ct = blockIdx.x * 64;
    const int rt = blockIdx.y * 64;

    float acc[4][4] = {};
    float acc2[4][4] = {};

    for (int k0 = 0; k0 < NDVIS; k0 += 32) {
        #pragma unroll
        for (int i = 0; i < 8; i++) {
            int flat = tid + 256 * i;
            int r = flat >> 5, k = flat & 31;
            A_s[r][k] = vis[(rt + r) * NDVIS + k0 + k];
        }
        #pragma unroll
        for (int i = 0; i < 8; i++) {
            int flat = tid + 256 * i;
            int k = flat >> 6, c = flat & 63;
            B_s[k][c] = img_W[(k0 + k) * NDH + ct + c];
        }
        __syncthreads();
        #pragma unroll
        for (int kk = 0; kk < 32; kk++) {
            float a[4];
            #pragma unroll
            for (int i = 0; i < 4; i++) a[i] = A_s[ty4 + i][kk];
            float4 bv = *(const float4*)&B_s[kk][tx4];
            float bb[4] = {bv.x, bv.y, bv.z, bv.w};
            #pragma unroll
            for (int i = 0; i < 4; i++)
                #pragma unroll
                for (int j = 0; j < 4; j++) acc[i][j] += a[i] * bb[j];
        }
        __syncthreads();
    }

    for (int k0 = 0; k0 < NDH; k0 += 32) {
        #pragma unroll
        for (int i = 0; i < 8; i++) {
            int flat = tid + 256 * i;
            int r = flat >> 5, k = flat & 31;
            A_s[r][k] = four[(rt + r) * NDH + k0 + k];
        }
        #pragma unroll
        for (int i = 0; i < 8; i++) {
            int flat = tid + 256 * i;
            int k = flat >> 6, c = flat & 63;
            B_s[k][c] = pos_W[(k0 + k) * NDH + ct + c];
        }
        __syncthreads();
        #pragma unroll
        for (int kk = 0; kk < 32; kk++) {
            float a[4];
            #pragma unroll
            for (int i = 0; i < 4; i++) a[i] = A_s[ty4 + i][kk];
            float4 bv = *(const float4*)&B_s[kk][tx4];
            float bb[4] = {bv.x, bv.y, bv.z, bv.w};
            #pragma unroll
            for (int i = 0; i < 4; i++)
                #pragma unroll
                for (int j = 0; j < 4; j++) acc2[i][j] += a[i] * bb[j];
        }
        __syncthreads();
    }

    #pragma unroll
    for (int i = 0; i < 4; i++) {
        int row = rt + ty4 + i;
        float4 v;
        float* vp = &v.x;
        #pragma unroll
        for (int j = 0; j < 4; j++) {
            int c = ct + tx4 + j;
            vp[j] = acc[i][j] + img_b[c] + gelu_f(acc2[i][j] + pos_b[c]);
        }
        *(float4*)&z[row * NDH + ct + tx4] = v;
    }
}

// ---------------------------------------------------------------- router
__global__ __launch_bounds__(256) void k_router(
    const float* __restrict__ z, const float* __restrict__ grad,
    const float* __restrict__ rW, const float* __restrict__ rb,
    float* __restrict__ gate, int* __restrict__ eidx, int* __restrict__ cnt)
{
    const int lane = threadIdx.x & 63;
    const int w = threadIdx.x >> 6;
    const int b = blockIdx.x * 4 + w;
    float l0 = 0.f, l1 = 0.f, l2 = 0.f, l3 = 0.f;
    #pragma unroll
    for (int i = 0; i < 4; i++) {
        int k = lane + 64 * i;
        float zv = z[b * NDH + k];
        float4 rw = *(const float4*)&rW[k * 4];
        l0 += zv * rw.x; l1 += zv * rw.y; l2 += zv * rw.z; l3 += zv * rw.w;
    }
    #pragma unroll
    for (int off = 32; off > 0; off >>= 1) {
        l0 += __shfl_xor(l0, off);
        l1 += __shfl_xor(l1, off);
        l2 += __shfl_xor(l2, off);
        l3 += __shfl_xor(l3, off);
    }
    if (lane == 0) {
        float g = grad[b];
        float l[4];
        l[0] = l0 + g * rW[256 * 4 + 0] + rb[0];
        l[1] = l1 + g * rW[256 * 4 + 1] + rb[1];
        l[2] = l2 + g * rW[256 * 4 + 2] + rb[2];
        l[3] = l3 + g * rW[256 * 4 + 3] + rb[3];
        int bi = 0; float best = l[0];
        #pragma unroll
        for (int e = 1; e < 4; e++) if (l[e] > best) { best = l[e]; bi = e; }
        float s = 0.f;
        #pragma unroll
        for (int e = 0; e < 4; e++) s += expf(l[e] - best);
        gate[b] = 1.0f / s;
        eidx[b] = bi;
        atomicAdd(&cnt[bi], 1);
    }
}

__global__ void k_zero(int* __restrict__ p) {
    if (threadIdx.x < 8) p[threadIdx.x] = 0;
}

__global__ void k_offs(const int* __restrict__ cnt, int* __restrict__ offs, int* __restrict__ cur) {
    if (threadIdx.x == 0) {
        int o = 0;
        for (int e = 0; e < NEXP; e++) { offs[e] = o; cur[e] = o; o += cnt[e]; }
    }
}

__global__ __launch_bounds__(256) void k_scatter(const int* __restrict__ eidx,
                                                 int* __restrict__ cur,
                                                 int* __restrict__ list) {
    int b = blockIdx.x * 256 + threadIdx.x;
    int e = eidx[b];
    int p = atomicAdd(&cur[e], 1);
    list[p] = b;
}

// ---------------------------------------------------------------- expert MLP on gathered rows
__global__ __launch_bounds__(256) void k_expert(
    const float* __restrict__ z, const float* __restrict__ gate,
    const int* __restrict__ cnt, const int* __restrict__ offs, const int* __restrict__ list,
    const float* __restrict__ W1, const float* __restrict__ b1,
    const float* __restrict__ W2, const float* __restrict__ b2,
    float* __restrict__ zf)
{
    const int e = blockIdx.x;
    const int n0 = blockIdx.y * 32;
    const int ne = cnt[e];
    if (n0 >= ne) return;

    __shared__ __align__(16) float z_s[256][32];
    __shared__ __align__(16) float h_s[128][32];
    __shared__ __align__(16) float w_s[4096];
    __shared__ int gr[32];

    const int tid = threadIdx.x;
    if (tid < 32) gr[tid] = (n0 + tid < ne) ? list[offs[e] + n0 + tid] : -1;
    __syncthreads();

    #pragma unroll 4
    for (int i = 0; i < 32; i++) {
        int row = gr[i];
        z_s[tid][i] = (row >= 0) ? z[row * NDH + tid] : 0.0f;
    }
    __syncthreads();

    const int tx1 = tid & 31, ty1 = tid >> 5;
    const int tx2 = tid & 63, ty2 = tid >> 6;
    float oacc[8][4] = {};

    for (int jc = 0; jc < 8; jc++) {
        float hacc[4][4] = {};
        for (int kc = 0; kc < 8; kc++) {
            __syncthreads();
            #pragma unroll
            for (int i = 0; i < 16; i++) {
                int flat = tid + 256 * i;
                int k = flat >> 7, j = flat & 127;
                w_s[k * 128 + j] = W1[(e * NDH + kc * 32 + k) * NHID + jc * 128 + j];
            }
            __syncthreads();
            #pragma unroll
            for (int kk = 0; kk < 32; kk++) {
                float4 av = *(const float4*)&z_s[kc * 32 + kk][ty1 * 4];
                float4 bv = *(const float4*)&w_s[kk * 128 + tx1 * 4];
                float aa[4] = {av.x, av.y, av.z, av.w};
                float bb[4] = {bv.x, bv.y, bv.z, bv.w};
                #pragma unroll
                for (int i = 0; i < 4; i++)
                    #pragma unroll
                    for (int j = 0; j < 4; j++) hacc[i][j] += aa[i] * bb[j];
            }
        }
        __syncthreads();
        #pragma unroll
        for (int j = 0; j < 4; j++) {
            int jl = tx1 * 4 + j;
            float bb1 = b1[e * NHID + jc * 128 + jl];
            float4 hv;
            hv.x = gelu_f(hacc[0][j] + bb1);
            hv.y = gelu_f(hacc[1][j] + bb1);
            hv.z = gelu_f(hacc[2][j] + bb1);
            hv.w = gelu_f(hacc[3][j] + bb1);
            *(float4*)&h_s[jl][ty1 * 4] = hv;
        }
        for (int kc2 = 0; kc2 < 8; kc2++) {
            __syncthreads();
            #pragma unroll
            for (int i = 0; i < 16; i++) {
                int flat = tid + 256 * i;
                int k = flat >> 8, c = flat & 255;
                w_s[k * 256 + c] = W2[(e * NHID + jc * 128 + kc2 * 16 + k) * NDH + c];
            }
            __syncthreads();
            #pragma unroll
            for (int kk = 0; kk < 16; kk++) {
                int kl = kc2 * 16 + kk;
                float4 a0 = *(const float4*)&h_s[kl][ty2 * 8];
                float4 a1 = *(const float4*)&h_s[kl][ty2 * 8 + 4];
                float4 bv = *(const float4*)&w_s[kk * 256 + tx2 * 4];
                float aa[8] = {a0.x, a0.y, a0.z, a0.w, a1.x, a1.y, a1.z, a1.w};
                float bb[4] = {bv.x, bv.y, bv.z, bv.w};
                #pragma unroll
                for (int i = 0; i < 8; i++)
                    #pragma unroll
                    for (int j = 0; j < 4; j++) oacc[i][j] += aa[i] * bb[j];
            }
        }
    }

    #pragma unroll
    for (int i = 0; i < 8; i++) {
        int r = ty2 * 8 + i;
        int row = gr[r];
        if (row < 0) continue;
        float gv = gate[row];
        int c = tx2 * 4;
        float4 zv = *(const float4*)&z[row * NDH + c];
        float4 b2v = *(const float4*)&b2[e * NDH + c];
        float4 res;
        res.x = zv.x + gv * (oacc[i][0] + b2v.x);
        res.y = zv.y + gv * (oacc[i][1] + b2v.y);
        res.z = zv.z + gv * (oacc[i][2] + b2v.z);
        res.w = zv.w + gv * (oacc[i][3] + b2v.w);
        *(float4*)&zf[row * NDH + c] = res;
    }
}

// ---------------------------------------------------------------- gene decoder stage 1:
// t = gelu(LN(zf @ gd_W1 + gd_b1)) -> emitted as bf16 hi/lo split pair
__global__ __launch_bounds__(256) void k_gd1(
    const float* __restrict__ zf, const float* __restrict__ W, const float* __restrict__ bias,
    const float* __restrict__ g, const float* __restrict__ beta,
    u16* __restrict__ t_hi, u16* __restrict__ t_lo)
{
    __shared__ __align__(16) float A_s[16][33];
    __shared__ __align__(16) float W_s[32 * 256];
    const int tid = threadIdx.x;
    const int tx = tid & 63, ty = tid >> 6;
    const int rt = blockIdx.x * 16;
    float acc[4][4] = {};

    for (int k0 = 0; k0 < NDH; k0 += 32) {
        #pragma unroll
        for (int i = 0; i < 2; i++) {
            int flat = tid + 256 * i;
            int r = flat >> 5, k = flat & 31;
            A_s[r][k] = zf[(rt + r) * NDH + k0 + k];
        }
        #pragma unroll
        for (int i = 0; i < 32; i++) {
            int flat = tid + 256 * i;
            int k = flat >> 8, c = flat & 255;
            W_s[k * 256 + c] = W[(k0 + k) * NDH + c];
        }
        __syncthreads();
        #pragma unroll
        for (int kk = 0; kk < 32; kk++) {
            float a[4];
            #pragma unroll
            for (int i = 0; i < 4; i++) a[i] = A_s[ty * 4 + i][kk];
            float4 bv = *(const float4*)&W_s[kk * 256 + tx * 4];
            float bb[4] = {bv.x, bv.y, bv.z, bv.w};
            #pragma unroll
            for (int i = 0; i < 4; i++)
                #pragma unroll
                for (int j = 0; j < 4; j++) acc[i][j] += a[i] * bb[j];
        }
        __syncthreads();
    }

    #pragma unroll
    for (int i = 0; i < 4; i++) {
        float v[4];
        #pragma unroll
        for (int j = 0; j < 4; j++) v[j] = acc[i][j] + bias[tx * 4 + j];
        float s1 = v[0] + v[1] + v[2] + v[3];
        float s2 = v[0]*v[0] + v[1]*v[1] + v[2]*v[2] + v[3]*v[3];
        #pragma unroll
        for (int off = 32; off > 0; off >>= 1) {
            s1 += __shfl_xor(s1, off);
            s2 += __shfl_xor(s2, off);
        }
        float mean = s1 * (1.0f / 256.0f);
        float var = s2 * (1.0f / 256.0f) - mean * mean;
        float rstd = rsqrtf(var + 1e-5f);
        int row = rt + ty * 4 + i;
        ushort4 hv, lv;
        u16* hp = (u16*)&hv.x;
        u16* lp = (u16*)&lv.x;
        #pragma unroll
        for (int j = 0; j < 4; j++) {
            int c = tx * 4 + j;
            float x = gelu_f(g[c] * (v[j] - mean) * rstd + beta[c]);
            u16 h = bf16_rtn(x);
            float hf = __uint_as_float((uint32_t)h << 16);
            hp[j] = h;
            lp[j] = bf16_rtn(x - hf);
        }
        *(ushort4*)&t_hi[row * NDH + tx * 4] = hv;
        *(ushort4*)&t_lo[row * NDH + tx * 4] = lv;
    }
}

// ---------------------------------------------------------------- W2 split/permute/pad:
// w2h/w2l[n][k] (n in [0,NPAD)): n<NHALF -> orig col 2n (mu), else orig col 2(n-NHALF)+1 (theta)
// rows with orig gene index >= NGENE are zero. b2p permuted the same way.
__global__ __launch_bounds__(256) void k_w2split(
    const float* __restrict__ W2, const float* __restrict__ b2,
    u16* __restrict__ w2h, u16* __restrict__ w2l, float* __restrict__ b2p)
{
    __shared__ float ls[32][33];
    const int tid = threadIdx.x;
    const int n0 = blockIdx.x * 32;

    const int nl_r = tid & 31, kl_r = tid >> 5;   // read layout: 32 n x 8 k-groups
    const int kg_w = tid & 7,  nl_w = tid >> 3;   // write layout: 32 n x 8 k-groups

    int n_r = n0 + nl_r;
    int gc_r; bool val_r;
    if (n_r < NHALF) { gc_r = 2 * n_r;            val_r = (n_r < NGENE); }
    else             { gc_r = 2 * (n_r - NHALF) + 1; val_r = ((n_r - NHALF) < NGENE); }

    int n_w = n0 + nl_w;

    for (int kc = 0; kc < 8; kc++) {
        __syncthreads();
        #pragma unroll
        for (int j = 0; j < 4; j++) {
            int k = kc * 32 + kl_r * 4 + j;
            ls[nl_r][kl_r * 4 + j] = val_r ? W2[(size_t)k * (2 * NGENE) + gc_r] : 0.0f;
        }
        __syncthreads();
        ushort4 hv, lv;
        u16* hp = (u16*)&hv.x;
        u16* lp = (u16*)&lv.x;
        #pragma unroll
        for (int j = 0; j < 4; j++) {
            float x = ls[nl_w][kg_w * 4 + j];
            u16 h = bf16_rtn(x);
            float hf = __uint_as_float((uint32_t)h << 16);
            hp[j] = h;
            lp[j] = bf16_rtn(x - hf);
        }
        *(ushort4*)&w2h[(size_t)n_w * NDH + kc * 32 + kg_w * 4] = hv;
        *(ushort4*)&w2l[(size_t)n_w * NDH + kc * 32 + kg_w * 4] = lv;
    }

    if (tid < 32) {
        int n = n0 + tid;
        int gc; bool val;
        if (n < NHALF) { gc = 2 * n;            val = (n < NGENE); }
        else           { gc = 2 * (n - NHALF) + 1; val = ((n - NHALF) < NGENE); }
        b2p[n] = val ? b2[gc] : 0.0f;
    }
}

// ---------------------------------------------------------------- gd2 as bf16x2-split MFMA GEMM
// C[16384 x NPAD] = (Ah+Al)[16384 x 256] @ (Bh+Bl)^T, 3-pass: AhBh + AhBl + AlBh.
// 128x128 tile, BK=64, 4 waves; wave w stages one LDS tile via global_load_lds(16B)
// with pre-swizzled global source (chunk ^= row&7) -> conflict-free ds_read_b128.
__global__ __launch_bounds__(256, 2) void k_gd2_mfma(
    const u16* __restrict__ tA_h, const u16* __restrict__ tA_l,
    const u16* __restrict__ w2h,  const u16* __restrict__ w2l,
    const float* __restrict__ b2p, const float* __restrict__ lib,
    float* __restrict__ mu_out, float* __restrict__ th_out)
{
    __shared__ __align__(16) u16 sA_h[128 * 64];
    __shared__ __align__(16) u16 sA_l[128 * 64];
    __shared__ __align__(16) u16 sB_h[128 * 64];
    __shared__ __align__(16) u16 sB_l[128 * 64];

    // XCD-aware bijective swizzle: nwg = 10240, 10240 % 8 == 0
    int bid = (int)blockIdx.x;
    bid = (bid & 7) * (NPAD * 128 / 128 / 8) + (bid >> 3);   // (bid&7)*1280 + bid/8
    const int bm = bid & 127;          // fast: row tiles share B panel in L2
    const int bn = bid >> 7;
    const int rt = bm * 128;
    const int ct = bn * 128;

    const int tid  = threadIdx.x;
    const int lane = tid & 63;
    const int w    = tid >> 6;
    const int wrr  = (w >> 1) * 64;    // wave's M offset in tile
    const int wcc  = (w & 1) * 64;     // wave's N offset in tile

    // staging role: one matrix per wave
    const u16* src = tA_h; u16* dstt = sA_h; int row0 = rt;
    if (w == 1)      { src = tA_l; dstt = sA_l; row0 = rt; }
    else if (w == 2) { src = w2h;  dstt = sB_h; row0 = ct; }
    else if (w == 3) { src = w2l;  dstt = sB_l; row0 = ct; }

    const int rsub = lane >> 3;               // row within 8-row group
    const int pc   = (lane & 7) ^ rsub;       // pre-swizzled source chunk

    f32x4 acc[4][4] = {};

    for (int ks = 0; ks < 4; ks++) {
        // stage 128 rows x 64 cols bf16 = 16 KB = 16 x (64 lanes x 16B)
        const char* gb = (const char*)(src + (size_t)(row0 + rsub) * NDH + ks * 64) + (pc << 4);
        #pragma unroll
        for (int i = 0; i < 16; i++) {
            __builtin_amdgcn_global_load_lds(
                (const __attribute__((address_space(1))) void*)(gb + i * (8 * NDH * 2)),
                (__attribute__((address_space(3))) void*)((char*)dstt + i * 1024),
                16, 0, 0);
        }
        __syncthreads();   // drains vmcnt before barrier -> tiles ready

        #pragma unroll
        for (int kk = 0; kk < 2; kk++) {
            bf16x8 Ah[4], Al[4];
            #pragma unroll
            for (int fm = 0; fm < 4; fm++) {
                const int r = wrr + fm * 16 + (lane & 15);
                const int c = kk * 4 + (lane >> 4);
                const int idx = r * 64 + ((c ^ (r & 7)) << 3);
                Ah[fm] = *(const bf16x8*)&sA_h[idx];
                Al[fm] = *(const bf16x8*)&sA_l[idx];
            }
            #pragma unroll
            for (int fn = 0; fn < 4; fn++) {
                const int r = wcc + fn * 16 + (lane & 15);
                const int c = kk * 4 + (lane >> 4);
                const int idx = r * 64 + ((c ^ (r & 7)) << 3);
                const bf16x8 Bh = *(const bf16x8*)&sB_h[idx];
                const bf16x8 Bl = *(const bf16x8*)&sB_l[idx];
                #pragma unroll
                for (int fm = 0; fm < 4; fm++) {
                    acc[fm][fn] = __builtin_amdgcn_mfma_f32_16x16x32_bf16(Ah[fm], Bh, acc[fm][fn], 0, 0, 0);
                    acc[fm][fn] = __builtin_amdgcn_mfma_f32_16x16x32_bf16(Ah[fm], Bl, acc[fm][fn], 0, 0, 0);
                    acc[fm][fn] = __builtin_amdgcn_mfma_f32_16x16x32_bf16(Al[fm], Bh, acc[fm][fn], 0, 0, 0);
                }
            }
        }
        __syncthreads();   // tile consumed, safe to restage
    }

    // epilogue: softplus, permuted column -> mu/theta. C/D layout (m89-verified):
    // col = lane&15, row = (lane>>4)*4 + reg
    const int mu_side = (ct < NHALF) ? 1 : 0;
    #pragma unroll
    for (int fn = 0; fn < 4; fn++) {
        const int np = ct + wcc + fn * 16 + (lane & 15);
        const int n  = mu_side ? np : (np - NHALF);
        const bool valid = (n < NGENE);
        const float bias = b2p[np];
        #pragma unroll
        for (int fm = 0; fm < 4; fm++) {
            const int rbase = rt + wrr + fm * 16 + ((lane >> 4) << 2);
            #pragma unroll
            for (int i = 0; i < 4; i++) {
                if (!valid) continue;
                const int row = rbase + i;
                const float sp = softplus_f(acc[fm][fn][i] + bias);
                if (mu_side) mu_out[(size_t)row * NGENE + n] = sp * lib[row] + 1e-6f;
                else         th_out[(size_t)row * NGENE + n] = sp + 1e-6f;
            }
        }
    }
}

// ---------------------------------------------------------------- func + align heads
__global__ __launch_bounds__(256) void k_heads(
    const float* __restrict__ zf,
    const float* __restrict__ apW1, const float* __restrict__ apb1,
    const float* __restrict__ apW2, const float* __restrict__ apb2,
    const float* __restrict__ fhW1, const float* __restrict__ fhb1,
    const float* __restrict__ fhW2, const float* __restrict__ fhb2,
    float* __restrict__ func_out, float* __restrict__ align_out)
{
    __shared__ float zs[8][256];
    __shared__ float ah[8][128];
    __shared__ float fh[8][64];
    const int tid = threadIdx.x;
    const int r0 = blockIdx.x * 8;

    #pragma unroll
    for (int i = 0; i < 8; i++) zs[i][tid] = zf[(r0 + i) * NDH + tid];
    __syncthreads();

    if (tid < 128) {
        int j = tid;
        float a[8] = {};
        for (int k = 0; k < 256; k++) {
            float w = apW1[k * 128 + j];
            #pragma unroll
            for (int i = 0; i < 8; i++) a[i] += zs[i][k] * w;
        }
        float bb = apb1[j];
        #pragma unroll
        for (int i = 0; i < 8; i++) ah[i][j] = gelu_f(a[i] + bb);
    } else if (tid < 192) {
        int j = tid - 128;
        float a[8] = {};
        for (int k = 0; k < 256; k++) {
            float w = fhW1[k * 64 + j];
            #pragma unroll
            for (int i = 0; i < 8; i++) a[i] += zs[i][k] * w;
        }
        float bb = fhb1[j];
        #pragma unroll
        for (int i = 0; i < 8; i++) fh[i][j] = gelu_f(a[i] + bb);
    }
    __syncthreads();

    if (tid < 240) {
        int r = tid / 30, j = tid % 30;
        float a = 0.f;
        for (int k = 0; k < 128; k++) a += ah[r][k] * apW2[k * 30 + j];
        align_out[(r0 + r) * NSCVI + j] = a + apb2[j];
    } else if (tid < 248) {
        int r = tid - 240;
        float a = 0.f;
        for (int k = 0; k < 64; k++) a += fh[r][k] * fhW2[k];
        func_out[r0 + r] = sigmoid_f(a + fhb2[0]);
    }
}

// ----------------------------------------------------------------
extern "C" void kernel_launch(void* const* d_in, const int* in_sizes, int n_in,
                              void* d_out, int out_size, void* d_ws, size_t ws_size,
                              hipStream_t stream) {
    const float* vis    = (const float*)d_in[0];
    const float* pos    = (const float*)d_in[1];
    const float* grad   = (const float*)d_in[2];
    const float* lib    = (const float*)d_in[3];
    const float* fB     = (const float*)d_in[4];
    const float* img_W  = (const float*)d_in[5];
    const float* img_b  = (const float*)d_in[6];
    const float* pos_W  = (const float*)d_in[7];
    const float* pos_b  = (const float*)d_in[8];
    const float* rW     = (const float*)d_in[9];
    const float* rb     = (const float*)d_in[10];
    const float* eW1    = (const float*)d_in[11];
    const float* eb1    = (const float*)d_in[12];
    const float* eW2    = (const float*)d_in[13];
    const float* eb2    = (const float*)d_in[14];
    const float* gdW1   = (const float*)d_in[15];
    const float* gdb1   = (const float*)d_in[16];
    const float* gdg    = (const float*)d_in[17];
    const float* gdbeta = (const float*)d_in[18];
    const float* gdW2   = (const float*)d_in[19];
    const float* gdb2   = (const float*)d_in[20];
    const float* apW1   = (const float*)d_in[21];
    const float* apb1   = (const float*)d_in[22];
    const float* apW2   = (const float*)d_in[23];
    const float* apb2   = (const float*)d_in[24];
    const float* fhW1   = (const float*)d_in[25];
    const float* fhb1   = (const float*)d_in[26];
    const float* fhW2   = (const float*)d_in[27];
    const float* fhb2   = (const float*)d_in[28];

    char* ws = (char*)d_ws;
    int* cnt  = (int*)(ws + 0);
    int* cur  = (int*)(ws + 16);
    int* offs = (int*)(ws + 32);
    size_t o = 256;
    float* gate = (float*)(ws + o); o += (size_t)NB * 4;
    int*   eidx = (int*)(ws + o);   o += (size_t)NB * 4;
    int*   list = (int*)(ws + o);   o += (size_t)NB * 4;
    float* z    = (float*)(ws + o); o += (size_t)NB * NDH * 4;
    float* zf   = (float*)(ws + o); o += (size_t)NB * NDH * 4;
    // region formerly "t" (16 MB): now W2 split buffers + permuted bias
    u16*   w2h  = (u16*)(ws + o);   o += (size_t)NPAD * NDH * 2;   // 5.24 MB
    u16*   w2l  = (u16*)(ws + o);   o += (size_t)NPAD * NDH * 2;   // 5.24 MB
    float* b2p  = (float*)(ws + o); o += (size_t)NPAD * 4;         // 40 KB
    o = (o + 255) & ~(size_t)255;
    // region "four" (16 MB): four is dead after k_z; overlay t_hi/t_lo (8 MB each)
    float* four = (float*)(ws + o);
    u16*   t_hi = (u16*)(ws + o);
    u16*   t_lo = (u16*)(ws + o + (size_t)NB * NDH * 2);
    o += (size_t)NB * NDH * 4;

    float* out       = (float*)d_out;
    float* mu_out    = out;
    float* th_out    = out + (size_t)NB * NGENE;
    float* func_out  = out + (size_t)2 * NB * NGENE;
    float* align_out = func_out + NB;

    k_zero<<<1, 64, 0, stream>>>(cnt);
    k_w2split<<<NPAD / 32, 256, 0, stream>>>(gdW2, gdb2, w2h, w2l, b2p);
    k_four<<<NB * 128 / 256, 256, 0, stream>>>(pos, fB, four);
    k_z<<<dim3(4, 256), 256, 0, stream>>>(vis, four, img_W, img_b, pos_W, pos_b, z);
    k_router<<<NB / 4, 256, 0, stream>>>(z, grad, rW, rb, gate, eidx, cnt);
    k_offs<<<1, 64, 0, stream>>>(cnt, offs, cur);
    k_scatter<<<NB / 256, 256, 0, stream>>>(eidx, cur, list);
    k_expert<<<dim3(NEXP, NB / 32), 256, 0, stream>>>(z, gate, cnt, offs, list,
                                                      eW1, eb1, eW2, eb2, zf);
    k_gd1<<<NB / 16, 256, 0, stream>>>(zf, gdW1, gdb1, gdg, gdbeta, t_hi, t_lo);
    k_gd2_mfma<<<NPAD * 128 / 128, 256, 0, stream>>>(t_hi, t_lo, w2h, w2l, b2p, lib,
                                                     mu_out, th_out);
    k_heads<<<NB / 8, 256, 0, stream>>>(zf, apW1, apb1, apW2, apb2,
                                        fhW1, fhb1, fhW2, fhb2, func_out, align_out);
}

// Round 2
// 2250.782 us; speedup vs baseline: 1.5758x; 1.5758x over previous
//
#include <hip/hip_runtime.h>
#include <math.h>
#include <stdint.h>

#define NB    16384
#define NDVIS 1024
#define NDH   256
#define NEXP  4
#define NGENE 5000
#define NHID  1024
#define NSCVI 30
#define NPAD  10240   // padded+permuted gd2 output cols: mu 0..5119, theta 5120..10239
#define NHALF 5120

typedef unsigned short u16;
typedef short bf16x8 __attribute__((ext_vector_type(8)));
typedef float f32x4 __attribute__((ext_vector_type(4)));

__device__ __forceinline__ float gelu_f(float x) {
    return 0.5f * x * (1.0f + erff(x * 0.7071067811865476f));
}
__device__ __forceinline__ float softplus_f(float x) {
    return fmaxf(x, 0.0f) + log1pf(expf(-fabsf(x)));
}
__device__ __forceinline__ float sigmoid_f(float x) {
    return 1.0f / (1.0f + expf(-x));
}
// round-to-nearest-even fp32 -> bf16
__device__ __forceinline__ u16 bf16_rtn(float x) {
    uint32_t u = __float_as_uint(x);
    uint32_t r = (u + 0x7FFFu + ((u >> 16) & 1u)) >> 16;
    return (u16)r;
}

// ---------------------------------------------------------------- fourier
__global__ __launch_bounds__(256) void k_four(const float* __restrict__ pos,
                                              const float* __restrict__ fB,
                                              float* __restrict__ four) {
    int idx = blockIdx.x * 256 + threadIdx.x;   // b*128 + j
    int b = idx >> 7, j = idx & 127;
    float p0 = pos[b * 3 + 0], p1 = pos[b * 3 + 1], p2 = pos[b * 3 + 2];
    float xp = 6.283185307179586f * (p0 * fB[j] + p1 * fB[128 + j] + p2 * fB[256 + j]);
    four[b * NDH + j]       = sinf(xp);
    four[b * NDH + 128 + j] = cosf(xp);
}

// ---------------------------------------------------------------- z = vis@img_W + img_b + gelu(four@pos_W + pos_b)
// also emits bf16 hi/lo split of z for the expert MFMA path
__global__ __launch_bounds__(256) void k_z(
    const float* __restrict__ vis, const float* __restrict__ four,
    const float* __restrict__ img_W, const float* __restrict__ img_b,
    const float* __restrict__ pos_W, const float* __restrict__ pos_b,
    float* __restrict__ z, u16* __restrict__ z_hi, u16* __restrict__ z_lo)
{
    __shared__ __align__(16) float A_s[64][33];
    __shared__ __align__(16) float B_s[32][64];
    const int tid = threadIdx.x;
    const int tx4 = (tid & 15) * 4;
    const int ty4 = (tid >> 4) * 4;
    const int ct = blockIdx.x * 64;
    const int rt = blockIdx.y * 64;

    float acc[4][4] = {};
    float acc2[4][4] = {};

    for (int k0 = 0; k0 < NDVIS; k0 += 32) {
        #pragma unroll
        for (int i = 0; i < 8; i++) {
            int flat = tid + 256 * i;
            int r = flat >> 5, k = flat & 31;
            A_s[r][k] = vis[(rt + r) * NDVIS + k0 + k];
        }
        #pragma unroll
        for (int i = 0; i < 8; i++) {
            int flat = tid + 256 * i;
            int k = flat >> 6, c = flat & 63;
            B_s[k][c] = img_W[(k0 + k) * NDH + ct + c];
        }
        __syncthreads();
        #pragma unroll
        for (int kk = 0; kk < 32; kk++) {
            float a[4];
            #pragma unroll
            for (int i = 0; i < 4; i++) a[i] = A_s[ty4 + i][kk];
            float4 bv = *(const float4*)&B_s[kk][tx4];
            float bb[4] = {bv.x, bv.y, bv.z, bv.w};
            #pragma unroll
            for (int i = 0; i < 4; i++)
                #pragma unroll
                for (int j = 0; j < 4; j++) acc[i][j] += a[i] * bb[j];
        }
        __syncthreads();
    }

    for (int k0 = 0; k0 < NDH; k0 += 32) {
        #pragma unroll
        for (int i = 0; i < 8; i++) {
            int flat = tid + 256 * i;
            int r = flat >> 5, k = flat & 31;
            A_s[r][k] = four[(rt + r) * NDH + k0 + k];
        }
        #pragma unroll
        for (int i = 0; i < 8; i++) {
            int flat = tid + 256 * i;
            int k = flat >> 6, c = flat & 63;
            B_s[k][c] = pos_W[(k0 + k) * NDH + ct + c];
        }
        __syncthreads();
        #pragma unroll
        for (int kk = 0; kk < 32; kk++) {
            float a[4];
            #pragma unroll
            for (int i = 0; i < 4; i++) a[i] = A_s[ty4 + i][kk];
            float4 bv = *(const float4*)&B_s[kk][tx4];
            float bb[4] = {bv.x, bv.y, bv.z, bv.w};
            #pragma unroll
            for (int i = 0; i < 4; i++)
                #pragma unroll
                for (int j = 0; j < 4; j++) acc2[i][j] += a[i] * bb[j];
        }
        __syncthreads();
    }

    #pragma unroll
    for (int i = 0; i < 4; i++) {
        int row = rt + ty4 + i;
        float4 v;
        float* vp = &v.x;
        ushort4 hv, lv;
        u16* hp = (u16*)&hv.x;
        u16* lp = (u16*)&lv.x;
        #pragma unroll
        for (int j = 0; j < 4; j++) {
            int c = ct + tx4 + j;
            float x = acc[i][j] + img_b[c] + gelu_f(acc2[i][j] + pos_b[c]);
            vp[j] = x;
            u16 h = bf16_rtn(x);
            float hf = __uint_as_float((uint32_t)h << 16);
            hp[j] = h;
            lp[j] = bf16_rtn(x - hf);
        }
        *(float4*)&z[row * NDH + ct + tx4] = v;
        *(ushort4*)&z_hi[row * NDH + ct + tx4] = hv;
        *(ushort4*)&z_lo[row * NDH + ct + tx4] = lv;
    }
}

// ---------------------------------------------------------------- router
__global__ __launch_bounds__(256) void k_router(
    const float* __restrict__ z, const float* __restrict__ grad,
    const float* __restrict__ rW, const float* __restrict__ rb,
    float* __restrict__ gate, int* __restrict__ eidx, int* __restrict__ cnt)
{
    const int lane = threadIdx.x & 63;
    const int w = threadIdx.x >> 6;
    const int b = blockIdx.x * 4 + w;
    float l0 = 0.f, l1 = 0.f, l2 = 0.f, l3 = 0.f;
    #pragma unroll
    for (int i = 0; i < 4; i++) {
        int k = lane + 64 * i;
        float zv = z[b * NDH + k];
        float4 rw = *(const float4*)&rW[k * 4];
        l0 += zv * rw.x; l1 += zv * rw.y; l2 += zv * rw.z; l3 += zv * rw.w;
    }
    #pragma unroll
    for (int off = 32; off > 0; off >>= 1) {
        l0 += __shfl_xor(l0, off);
        l1 += __shfl_xor(l1, off);
        l2 += __shfl_xor(l2, off);
        l3 += __shfl_xor(l3, off);
    }
    if (lane == 0) {
        float g = grad[b];
        float l[4];
        l[0] = l0 + g * rW[256 * 4 + 0] + rb[0];
        l[1] = l1 + g * rW[256 * 4 + 1] + rb[1];
        l[2] = l2 + g * rW[256 * 4 + 2] + rb[2];
        l[3] = l3 + g * rW[256 * 4 + 3] + rb[3];
        int bi = 0; float best = l[0];
        #pragma unroll
        for (int e = 1; e < 4; e++) if (l[e] > best) { best = l[e]; bi = e; }
        float s = 0.f;
        #pragma unroll
        for (int e = 0; e < 4; e++) s += expf(l[e] - best);
        gate[b] = 1.0f / s;
        eidx[b] = bi;
        atomicAdd(&cnt[bi], 1);
    }
}

__global__ void k_zero(int* __restrict__ p) {
    if (threadIdx.x < 8) p[threadIdx.x] = 0;
}

__global__ void k_offs(const int* __restrict__ cnt, int* __restrict__ offs, int* __restrict__ cur) {
    if (threadIdx.x == 0) {
        int o = 0;
        for (int e = 0; e < NEXP; e++) { offs[e] = o; cur[e] = o; o += cnt[e]; }
    }
}

__global__ __launch_bounds__(256) void k_scatter(const int* __restrict__ eidx,
                                                 int* __restrict__ cur,
                                                 int* __restrict__ list) {
    int b = blockIdx.x * 256 + threadIdx.x;
    int e = eidx[b];
    int p = atomicAdd(&cur[e], 1);
    list[p] = b;
}

// ---------------------------------------------------------------- generic weight transpose+split
// src: [E][K][N] fp32  ->  dh/dl: [E][N][K] bf16 hi/lo.  grid: (E, N/32, K/32), 256 thr
__global__ __launch_bounds__(256) void k_wsplit(const float* __restrict__ src,
                                                u16* __restrict__ dh, u16* __restrict__ dl,
                                                int K, int N) {
    __shared__ float ls[32][33];
    const int tid = threadIdx.x;
    const int e = blockIdx.x, n0 = blockIdx.y * 32, k0 = blockIdx.z * 32;
    const int kr = tid >> 3, nc = (tid & 7) * 4;
    float4 v = *(const float4*)&src[((size_t)e * K + k0 + kr) * N + n0 + nc];
    ls[kr][nc + 0] = v.x; ls[kr][nc + 1] = v.y; ls[kr][nc + 2] = v.z; ls[kr][nc + 3] = v.w;
    __syncthreads();
    const int nr = tid >> 3, kc = (tid & 7) * 4;
    ushort4 hv, lv;
    u16* hp = (u16*)&hv.x;
    u16* lp = (u16*)&lv.x;
    #pragma unroll
    for (int j = 0; j < 4; j++) {
        float x = ls[kc + j][nr];
        u16 h = bf16_rtn(x);
        float hf = __uint_as_float((uint32_t)h << 16);
        hp[j] = h;
        lp[j] = bf16_rtn(x - hf);
    }
    size_t oidx = ((size_t)e * N + n0 + nr) * K + k0 + kc;
    *(ushort4*)&dh[oidx] = hv;
    *(ushort4*)&dl[oidx] = lv;
}

// ---------------------------------------------------------------- expert GEMM1 (MFMA):
// H[g] = gelu(z[list[g]] @ W1[e] + b1[e]),  H stored bf16 hi/lo in gathered order.
// 128x128 tile, K=256 (4 steps of BK=64). Same staging/swizzle template as k_gd2_mfma.
__global__ __launch_bounds__(256, 2) void k_exp1(
    const u16* __restrict__ z_hi, const u16* __restrict__ z_lo,
    const u16* __restrict__ w1t_h, const u16* __restrict__ w1t_l,
    const float* __restrict__ b1,
    const int* __restrict__ cnt, const int* __restrict__ offs, const int* __restrict__ list,
    u16* __restrict__ H_hi, u16* __restrict__ H_lo)
{
    __shared__ __align__(16) u16 sA_h[128 * 64];
    __shared__ __align__(16) u16 sA_l[128 * 64];
    __shared__ __align__(16) u16 sB_h[128 * 64];
    __shared__ __align__(16) u16 sB_l[128 * 64];

    const int e  = blockIdx.x >> 3;
    const int nt = blockIdx.x & 7;
    const int ne = cnt[e];
    const int n0 = blockIdx.y * 128;
    if (n0 >= ne) return;
    const int base = offs[e];

    const int tid = threadIdx.x, lane = tid & 63, w = tid >> 6;
    const int wrr = (w >> 1) * 64, wcc = (w & 1) * 64;
    const int rsub = lane >> 3, pc = (lane & 7) ^ rsub;

    const char* srcb;
    u16* dstt;
    uint32_t rowoff[16];
    if (w < 2) {
        srcb = (const char*)(w == 0 ? z_hi : z_lo);
        dstt = (w == 0) ? sA_h : sA_l;
        #pragma unroll
        for (int i = 0; i < 16; i++) {
            int g = base + n0 + i * 8 + rsub;
            g = (g < NB) ? g : (NB - 1);
            rowoff[i] = (uint32_t)list[g] * 512u;      // z row stride = 256 u16 = 512 B
        }
    } else {
        srcb = (const char*)(w == 2 ? w1t_h : w1t_l);
        dstt = (w == 2) ? sB_h : sB_l;
        #pragma unroll
        for (int i = 0; i < 16; i++)
            rowoff[i] = (uint32_t)(e * NHID + nt * 128 + i * 8 + rsub) * 512u;
    }

    f32x4 acc[4][4] = {};

    for (int ks = 0; ks < 4; ks++) {
        const int koff = ks * 128 + (pc << 4);
        #pragma unroll
        for (int i = 0; i < 16; i++) {
            __builtin_amdgcn_global_load_lds(
                (const __attribute__((address_space(1))) void*)(srcb + rowoff[i] + koff),
                (__attribute__((address_space(3))) void*)((char*)dstt + i * 1024),
                16, 0, 0);
        }
        __syncthreads();

        #pragma unroll
        for (int kk = 0; kk < 2; kk++) {
            bf16x8 Ah[4], Al[4];
            #pragma unroll
            for (int fm = 0; fm < 4; fm++) {
                const int r = wrr + fm * 16 + (lane & 15);
                const int c = kk * 4 + (lane >> 4);
                const int idx = r * 64 + ((c ^ (r & 7)) << 3);
                Ah[fm] = *(const bf16x8*)&sA_h[idx];
                Al[fm] = *(const bf16x8*)&sA_l[idx];
            }
            #pragma unroll
            for (int fn = 0; fn < 4; fn++) {
                const int r = wcc + fn * 16 + (lane & 15);
                const int c = kk * 4 + (lane >> 4);
                const int idx = r * 64 + ((c ^ (r & 7)) << 3);
                const bf16x8 Bh = *(const bf16x8*)&sB_h[idx];
                const bf16x8 Bl = *(const bf16x8*)&sB_l[idx];
                #pragma unroll
                for (int fm = 0; fm < 4; fm++) {
                    acc[fm][fn] = __builtin_amdgcn_mfma_f32_16x16x32_bf16(Ah[fm], Bh, acc[fm][fn], 0, 0, 0);
                    acc[fm][fn] = __builtin_amdgcn_mfma_f32_16x16x32_bf16(Ah[fm], Bl, acc[fm][fn], 0, 0, 0);
                    acc[fm][fn] = __builtin_amdgcn_mfma_f32_16x16x32_bf16(Al[fm], Bh, acc[fm][fn], 0, 0, 0);
                }
            }
        }
        __syncthreads();
    }

    // epilogue: gelu(+b1) -> bf16 hi/lo into H (gathered order), guard tail rows
    #pragma unroll
    for (int fn = 0; fn < 4; fn++) {
        const int nl = wcc + fn * 16 + (lane & 15);
        const float bb = b1[e * NHID + nt * 128 + nl];
        #pragma unroll
        for (int fm = 0; fm < 4; fm++) {
            const int rb = wrr + fm * 16 + ((lane >> 4) << 2);
            #pragma unroll
            for (int i = 0; i < 4; i++) {
                const int rl = rb + i;
                if (n0 + rl < ne) {
                    float x = gelu_f(acc[fm][fn][i] + bb);
                    u16 h = bf16_rtn(x);
                    float hf = __uint_as_float((uint32_t)h << 16);
                    size_t idx = (size_t)(base + n0 + rl) * NHID + nt * 128 + nl;
                    H_hi[idx] = h;
                    H_lo[idx] = bf16_rtn(x - hf);
                }
            }
        }
    }
}

// ---------------------------------------------------------------- expert GEMM2 (MFMA):
// zf[list[g]] = z[list[g]] + gate * (H[g] @ W2[e] + b2[e]).  K=1024 (16 steps).
__global__ __launch_bounds__(256, 2) void k_exp2(
    const u16* __restrict__ H_hi, const u16* __restrict__ H_lo,
    const u16* __restrict__ w2et_h, const u16* __restrict__ w2et_l,
    const float* __restrict__ b2, const float* __restrict__ z,
    const float* __restrict__ gate,
    const int* __restrict__ cnt, const int* __restrict__ offs, const int* __restrict__ list,
    float* __restrict__ zf)
{
    __shared__ __align__(16) u16 sA_h[128 * 64];
    __shared__ __align__(16) u16 sA_l[128 * 64];
    __shared__ __align__(16) u16 sB_h[128 * 64];
    __shared__ __align__(16) u16 sB_l[128 * 64];

    const int e  = blockIdx.x >> 1;
    const int nt = blockIdx.x & 1;
    const int ne = cnt[e];
    const int n0 = blockIdx.y * 128;
    if (n0 >= ne) return;
    const int base = offs[e];

    const int tid = threadIdx.x, lane = tid & 63, w = tid >> 6;
    const int wrr = (w >> 1) * 64, wcc = (w & 1) * 64;
    const int rsub = lane >> 3, pc = (lane & 7) ^ rsub;

    const char* srcb;
    u16* dstt;
    uint32_t rowoff[16];
    if (w < 2) {
        srcb = (const char*)(w == 0 ? H_hi : H_lo);
        dstt = (w == 0) ? sA_h : sA_l;
        #pragma unroll
        for (int i = 0; i < 16; i++) {
            int g = base + n0 + i * 8 + rsub;
            g = (g < NB) ? g : (NB - 1);
            rowoff[i] = (uint32_t)g * 2048u;           // H row stride = 1024 u16 = 2048 B
        }
    } else {
        srcb = (const char*)(w == 2 ? w2et_h : w2et_l);
        dstt = (w == 2) ? sB_h : sB_l;
        #pragma unroll
        for (int i = 0; i < 16; i++)
            rowoff[i] = (uint32_t)(e * NDH + nt * 128 + i * 8 + rsub) * 2048u;
    }

    f32x4 acc[4][4] = {};

    for (int ks = 0; ks < 16; ks++) {
        const int koff = ks * 128 + (pc << 4);
        #pragma unroll
        for (int i = 0; i < 16; i++) {
            __builtin_amdgcn_global_load_lds(
                (const __attribute__((address_space(1))) void*)(srcb + rowoff[i] + koff),
                (__attribute__((address_space(3))) void*)((char*)dstt + i * 1024),
                16, 0, 0);
        }
        __syncthreads();

        #pragma unroll
        for (int kk = 0; kk < 2; kk++) {
            bf16x8 Ah[4], Al[4];
            #pragma unroll
            for (int fm = 0; fm < 4; fm++) {
                const int r = wrr + fm * 16 + (lane & 15);
                const int c = kk * 4 + (lane >> 4);
                const int idx = r * 64 + ((c ^ (r & 7)) << 3);
                Ah[fm] = *(const bf16x8*)&sA_h[idx];
                Al[fm] = *(const bf16x8*)&sA_l[idx];
            }
            #pragma unroll
            for (int fn = 0; fn < 4; fn++) {
                const int r = wcc + fn * 16 + (lane & 15);
                const int c = kk * 4 + (lane >> 4);
                const int idx = r * 64 + ((c ^ (r & 7)) << 3);
                const bf16x8 Bh = *(const bf16x8*)&sB_h[idx];
                const bf16x8 Bl = *(const bf16x8*)&sB_l[idx];
                #pragma unroll
                for (int fm = 0; fm < 4; fm++) {
                    acc[fm][fn] = __builtin_amdgcn_mfma_f32_16x16x32_bf16(Ah[fm], Bh, acc[fm][fn], 0, 0, 0);
                    acc[fm][fn] = __builtin_amdgcn_mfma_f32_16x16x32_bf16(Ah[fm], Bl, acc[fm][fn], 0, 0, 0);
                    acc[fm][fn] = __builtin_amdgcn_mfma_f32_16x16x32_bf16(Al[fm], Bh, acc[fm][fn], 0, 0, 0);
                }
            }
        }
        __syncthreads();
    }

    // epilogue: scatter zf[row] = z[row] + gate[row] * (acc + b2)
    #pragma unroll
    for (int fn = 0; fn < 4; fn++) {
        const int nc = nt * 128 + wcc + fn * 16 + (lane & 15);
        const float bb = b2[e * NDH + nc];
        #pragma unroll
        for (int fm = 0; fm < 4; fm++) {
            const int rb = wrr + fm * 16 + ((lane >> 4) << 2);
            #pragma unroll
            for (int i = 0; i < 4; i++) {
                const int rl = rb + i;
                if (n0 + rl < ne) {
                    const int row = list[base + n0 + rl];
                    const float o = acc[fm][fn][i] + bb;
                    zf[(size_t)row * NDH + nc] = z[(size_t)row * NDH + nc] + gate[row] * o;
                }
            }
        }
    }
}

// ---------------------------------------------------------------- gene decoder stage 1:
// t = gelu(LN(zf @ gd_W1 + gd_b1)) -> emitted as bf16 hi/lo split pair
__global__ __launch_bounds__(256) void k_gd1(
    const float* __restrict__ zf, const float* __restrict__ W, const float* __restrict__ bias,
    const float* __restrict__ g, const float* __restrict__ beta,
    u16* __restrict__ t_hi, u16* __restrict__ t_lo)
{
    __shared__ __align__(16) float A_s[16][33];
    __shared__ __align__(16) float W_s[32 * 256];
    const int tid = threadIdx.x;
    const int tx = tid & 63, ty = tid >> 6;
    const int rt = blockIdx.x * 16;
    float acc[4][4] = {};

    for (int k0 = 0; k0 < NDH; k0 += 32) {
        #pragma unroll
        for (int i = 0; i < 2; i++) {
            int flat = tid + 256 * i;
            int r = flat >> 5, k = flat & 31;
            A_s[r][k] = zf[(rt + r) * NDH + k0 + k];
        }
        #pragma unroll
        for (int i = 0; i < 32; i++) {
            int flat = tid + 256 * i;
            int k = flat >> 8, c = flat & 255;
            W_s[k * 256 + c] = W[(k0 + k) * NDH + c];
        }
        __syncthreads();
        #pragma unroll
        for (int kk = 0; kk < 32; kk++) {
            float a[4];
            #pragma unroll
            for (int i = 0; i < 4; i++) a[i] = A_s[ty * 4 + i][kk];
            float4 bv = *(const float4*)&W_s[kk * 256 + tx * 4];
            float bb[4] = {bv.x, bv.y, bv.z, bv.w};
            #pragma unroll
            for (int i = 0; i < 4; i++)
                #pragma unroll
                for (int j = 0; j < 4; j++) acc[i][j] += a[i] * bb[j];
        }
        __syncthreads();
    }

    #pragma unroll
    for (int i = 0; i < 4; i++) {
        float v[4];
        #pragma unroll
        for (int j = 0; j < 4; j++) v[j] = acc[i][j] + bias[tx * 4 + j];
        float s1 = v[0] + v[1] + v[2] + v[3];
        float s2 = v[0]*v[0] + v[1]*v[1] + v[2]*v[2] + v[3]*v[3];
        #pragma unroll
        for (int off = 32; off > 0; off >>= 1) {
            s1 += __shfl_xor(s1, off);
            s2 += __shfl_xor(s2, off);
        }
        float mean = s1 * (1.0f / 256.0f);
        float var = s2 * (1.0f / 256.0f) - mean * mean;
        float rstd = rsqrtf(var + 1e-5f);
        int row = rt + ty * 4 + i;
        ushort4 hv, lv;
        u16* hp = (u16*)&hv.x;
        u16* lp = (u16*)&lv.x;
        #pragma unroll
        for (int j = 0; j < 4; j++) {
            int c = tx * 4 + j;
            float x = gelu_f(g[c] * (v[j] - mean) * rstd + beta[c]);
            u16 h = bf16_rtn(x);
            float hf = __uint_as_float((uint32_t)h << 16);
            hp[j] = h;
            lp[j] = bf16_rtn(x - hf);
        }
        *(ushort4*)&t_hi[row * NDH + tx * 4] = hv;
        *(ushort4*)&t_lo[row * NDH + tx * 4] = lv;
    }
}

// ---------------------------------------------------------------- W2 split/permute/pad (gd2 B operand)
__global__ __launch_bounds__(256) void k_w2split(
    const float* __restrict__ W2, const float* __restrict__ b2,
    u16* __restrict__ w2h, u16* __restrict__ w2l, float* __restrict__ b2p)
{
    __shared__ float ls[32][33];
    const int tid = threadIdx.x;
    const int n0 = blockIdx.x * 32;

    const int nl_r = tid & 31, kl_r = tid >> 5;
    const int kg_w = tid & 7,  nl_w = tid >> 3;

    int n_r = n0 + nl_r;
    int gc_r; bool val_r;
    if (n_r < NHALF) { gc_r = 2 * n_r;            val_r = (n_r < NGENE); }
    else             { gc_r = 2 * (n_r - NHALF) + 1; val_r = ((n_r - NHALF) < NGENE); }

    int n_w = n0 + nl_w;

    for (int kc = 0; kc < 8; kc++) {
        __syncthreads();
        #pragma unroll
        for (int j = 0; j < 4; j++) {
            int k = kc * 32 + kl_r * 4 + j;
            ls[nl_r][kl_r * 4 + j] = val_r ? W2[(size_t)k * (2 * NGENE) + gc_r] : 0.0f;
        }
        __syncthreads();
        ushort4 hv, lv;
        u16* hp = (u16*)&hv.x;
        u16* lp = (u16*)&lv.x;
        #pragma unroll
        for (int j = 0; j < 4; j++) {
            float x = ls[nl_w][kg_w * 4 + j];
            u16 h = bf16_rtn(x);
            float hf = __uint_as_float((uint32_t)h << 16);
            hp[j] = h;
            lp[j] = bf16_rtn(x - hf);
        }
        *(ushort4*)&w2h[(size_t)n_w * NDH + kc * 32 + kg_w * 4] = hv;
        *(ushort4*)&w2l[(size_t)n_w * NDH + kc * 32 + kg_w * 4] = lv;
    }

    if (tid < 32) {
        int n = n0 + tid;
        int gc; bool val;
        if (n < NHALF) { gc = 2 * n;            val = (n < NGENE); }
        else           { gc = 2 * (n - NHALF) + 1; val = ((n - NHALF) < NGENE); }
        b2p[n] = val ? b2[gc] : 0.0f;
    }
}

// ---------------------------------------------------------------- gd2 as bf16x2-split MFMA GEMM
__global__ __launch_bounds__(256, 2) void k_gd2_mfma(
    const u16* __restrict__ tA_h, const u16* __restrict__ tA_l,
    const u16* __restrict__ w2h,  const u16* __restrict__ w2l,
    const float* __restrict__ b2p, const float* __restrict__ lib,
    float* __restrict__ mu_out, float* __restrict__ th_out)
{
    __shared__ __align__(16) u16 sA_h[128 * 64];
    __shared__ __align__(16) u16 sA_l[128 * 64];
    __shared__ __align__(16) u16 sB_h[128 * 64];
    __shared__ __align__(16) u16 sB_l[128 * 64];

    int bid = (int)blockIdx.x;
    bid = (bid & 7) * (NPAD * 128 / 128 / 8) + (bid >> 3);
    const int bm = bid & 127;
    const int bn = bid >> 7;
    const int rt = bm * 128;
    const int ct = bn * 128;

    const int tid  = threadIdx.x;
    const int lane = tid & 63;
    const int w    = tid >> 6;
    const int wrr  = (w >> 1) * 64;
    const int wcc  = (w & 1) * 64;

    const u16* src = tA_h; u16* dstt = sA_h; int row0 = rt;
    if (w == 1)      { src = tA_l; dstt = sA_l; row0 = rt; }
    else if (w == 2) { src = w2h;  dstt = sB_h; row0 = ct; }
    else if (w == 3) { src = w2l;  dstt = sB_l; row0 = ct; }

    const int rsub = lane >> 3;
    const int pc   = (lane & 7) ^ rsub;

    f32x4 acc[4][4] = {};

    for (int ks = 0; ks < 4; ks++) {
        const char* gb = (const char*)(src + (size_t)(row0 + rsub) * NDH + ks * 64) + (pc << 4);
        #pragma unroll
        for (int i = 0; i < 16; i++) {
            __builtin_amdgcn_global_load_lds(
                (const __attribute__((address_space(1))) void*)(gb + i * (8 * NDH * 2)),
                (__attribute__((address_space(3))) void*)((char*)dstt + i * 1024),
                16, 0, 0);
        }
        __syncthreads();

        #pragma unroll
        for (int kk = 0; kk < 2; kk++) {
            bf16x8 Ah[4], Al[4];
            #pragma unroll
            for (int fm = 0; fm < 4; fm++) {
                const int r = wrr + fm * 16 + (lane & 15);
                const int c = kk * 4 + (lane >> 4);
                const int idx = r * 64 + ((c ^ (r & 7)) << 3);
                Ah[fm] = *(const bf16x8*)&sA_h[idx];
                Al[fm] = *(const bf16x8*)&sA_l[idx];
            }
            #pragma unroll
            for (int fn = 0; fn < 4; fn++) {
                const int r = wcc + fn * 16 + (lane & 15);
                const int c = kk * 4 + (lane >> 4);
                const int idx = r * 64 + ((c ^ (r & 7)) << 3);
                const bf16x8 Bh = *(const bf16x8*)&sB_h[idx];
                const bf16x8 Bl = *(const bf16x8*)&sB_l[idx];
                #pragma unroll
                for (int fm = 0; fm < 4; fm++) {
                    acc[fm][fn] = __builtin_amdgcn_mfma_f32_16x16x32_bf16(Ah[fm], Bh, acc[fm][fn], 0, 0, 0);
                    acc[fm][fn] = __builtin_amdgcn_mfma_f32_16x16x32_bf16(Ah[fm], Bl, acc[fm][fn], 0, 0, 0);
                    acc[fm][fn] = __builtin_amdgcn_mfma_f32_16x16x32_bf16(Al[fm], Bh, acc[fm][fn], 0, 0, 0);
                }
            }
        }
        __syncthreads();
    }

    const int mu_side = (ct < NHALF) ? 1 : 0;
    #pragma unroll
    for (int fn = 0; fn < 4; fn++) {
        const int np = ct + wcc + fn * 16 + (lane & 15);
        const int n  = mu_side ? np : (np - NHALF);
        const bool valid = (n < NGENE);
        const float bias = b2p[np];
        #pragma unroll
        for (int fm = 0; fm < 4; fm++) {
            const int rbase = rt + wrr + fm * 16 + ((lane >> 4) << 2);
            #pragma unroll
            for (int i = 0; i < 4; i++) {
                if (!valid) continue;
                const int row = rbase + i;
                const float sp = softplus_f(acc[fm][fn][i] + bias);
                if (mu_side) mu_out[(size_t)row * NGENE + n] = sp * lib[row] + 1e-6f;
                else         th_out[(size_t)row * NGENE + n] = sp + 1e-6f;
            }
        }
    }
}

// ---------------------------------------------------------------- func + align heads
__global__ __launch_bounds__(256) void k_heads(
    const float* __restrict__ zf,
    const float* __restrict__ apW1, const float* __restrict__ apb1,
    const float* __restrict__ apW2, const float* __restrict__ apb2,
    const float* __restrict__ fhW1, const float* __restrict__ fhb1,
    const float* __restrict__ fhW2, const float* __restrict__ fhb2,
    float* __restrict__ func_out, float* __restrict__ align_out)
{
    __shared__ float zs[8][256];
    __shared__ float ah[8][128];
    __shared__ float fh[8][64];
    const int tid = threadIdx.x;
    const int r0 = blockIdx.x * 8;

    #pragma unroll
    for (int i = 0; i < 8; i++) zs[i][tid] = zf[(r0 + i) * NDH + tid];
    __syncthreads();

    if (tid < 128) {
        int j = tid;
        float a[8] = {};
        for (int k = 0; k < 256; k++) {
            float w = apW1[k * 128 + j];
            #pragma unroll
            for (int i = 0; i < 8; i++) a[i] += zs[i][k] * w;
        }
        float bb = apb1[j];
        #pragma unroll
        for (int i = 0; i < 8; i++) ah[i][j] = gelu_f(a[i] + bb);
    } else if (tid < 192) {
        int j = tid - 128;
        float a[8] = {};
        for (int k = 0; k < 256; k++) {
            float w = fhW1[k * 64 + j];
            #pragma unroll
            for (int i = 0; i < 8; i++) a[i] += zs[i][k] * w;
        }
        float bb = fhb1[j];
        #pragma unroll
        for (int i = 0; i < 8; i++) fh[i][j] = gelu_f(a[i] + bb);
    }
    __syncthreads();

    if (tid < 240) {
        int r = tid / 30, j = tid % 30;
        float a = 0.f;
        for (int k = 0; k < 128; k++) a += ah[r][k] * apW2[k * 30 + j];
        align_out[(r0 + r) * NSCVI + j] = a + apb2[j];
    } else if (tid < 248) {
        int r = tid - 240;
        float a = 0.f;
        for (int k = 0; k < 64; k++) a += fh[r][k] * fhW2[k];
        func_out[r0 + r] = sigmoid_f(a + fhb2[0]);
    }
}

// ----------------------------------------------------------------
extern "C" void kernel_launch(void* const* d_in, const int* in_sizes, int n_in,
                              void* d_out, int out_size, void* d_ws, size_t ws_size,
                              hipStream_t stream) {
    const float* vis    = (const float*)d_in[0];
    const float* pos    = (const float*)d_in[1];
    const float* grad   = (const float*)d_in[2];
    const float* lib    = (const float*)d_in[3];
    const float* fB     = (const float*)d_in[4];
    const float* img_W  = (const float*)d_in[5];
    const float* img_b  = (const float*)d_in[6];
    const float* pos_W  = (const float*)d_in[7];
    const float* pos_b  = (const float*)d_in[8];
    const float* rW     = (const float*)d_in[9];
    const float* rb     = (const float*)d_in[10];
    const float* eW1    = (const float*)d_in[11];
    const float* eb1    = (const float*)d_in[12];
    const float* eW2    = (const float*)d_in[13];
    const float* eb2    = (const float*)d_in[14];
    const float* gdW1   = (const float*)d_in[15];
    const float* gdb1   = (const float*)d_in[16];
    const float* gdg    = (const float*)d_in[17];
    const float* gdbeta = (const float*)d_in[18];
    const float* gdW2   = (const float*)d_in[19];
    const float* gdb2   = (const float*)d_in[20];
    const float* apW1   = (const float*)d_in[21];
    const float* apb1   = (const float*)d_in[22];
    const float* apW2   = (const float*)d_in[23];
    const float* apb2   = (const float*)d_in[24];
    const float* fhW1   = (const float*)d_in[25];
    const float* fhb1   = (const float*)d_in[26];
    const float* fhW2   = (const float*)d_in[27];
    const float* fhb2   = (const float*)d_in[28];

    char* ws = (char*)d_ws;
    int* cnt  = (int*)(ws + 0);
    int* cur  = (int*)(ws + 16);
    int* offs = (int*)(ws + 32);
    size_t o = 256;
    float* gate = (float*)(ws + o); o += (size_t)NB * 4;
    int*   eidx = (int*)(ws + o);   o += (size_t)NB * 4;
    int*   list = (int*)(ws + o);   o += (size_t)NB * 4;
    float* z    = (float*)(ws + o); o += (size_t)NB * NDH * 4;
    float* zf   = (float*)(ws + o); o += (size_t)NB * NDH * 4;
    u16*   z_hi = (u16*)(ws + o);   o += (size_t)NB * NDH * 2;
    u16*   z_lo = (u16*)(ws + o);   o += (size_t)NB * NDH * 2;
    u16*   w1t_h = (u16*)(ws + o);  o += (size_t)NEXP * NHID * NDH * 2;   // [4][1024][256]
    u16*   w1t_l = (u16*)(ws + o);  o += (size_t)NEXP * NHID * NDH * 2;
    u16*   w2et_h = (u16*)(ws + o); o += (size_t)NEXP * NDH * NHID * 2;   // [4][256][1024]
    u16*   w2et_l = (u16*)(ws + o); o += (size_t)NEXP * NDH * NHID * 2;
    u16*   w2h  = (u16*)(ws + o);   o += (size_t)NPAD * NDH * 2;
    u16*   w2l  = (u16*)(ws + o);   o += (size_t)NPAD * NDH * 2;
    float* b2p  = (float*)(ws + o); o += (size_t)NPAD * 4;
    o = (o + 255) & ~(size_t)255;
    // region "four" (16 MB): dead after k_z; overlay t_hi/t_lo
    float* four = (float*)(ws + o);
    u16*   t_hi = (u16*)(ws + o);
    u16*   t_lo = (u16*)(ws + o + (size_t)NB * NDH * 2);
    o += (size_t)NB * NDH * 4;
    u16*   H_hi = (u16*)(ws + o);   o += (size_t)NB * NHID * 2;           // 32 MB
    u16*   H_lo = (u16*)(ws + o);   o += (size_t)NB * NHID * 2;           // 32 MB

    float* out       = (float*)d_out;
    float* mu_out    = out;
    float* th_out    = out + (size_t)NB * NGENE;
    float* func_out  = out + (size_t)2 * NB * NGENE;
    float* align_out = func_out + NB;

    k_zero<<<1, 64, 0, stream>>>(cnt);
    k_wsplit<<<dim3(NEXP, NHID / 32, NDH / 32), 256, 0, stream>>>(eW1, w1t_h, w1t_l, NDH, NHID);
    k_wsplit<<<dim3(NEXP, NDH / 32, NHID / 32), 256, 0, stream>>>(eW2, w2et_h, w2et_l, NHID, NDH);
    k_w2split<<<NPAD / 32, 256, 0, stream>>>(gdW2, gdb2, w2h, w2l, b2p);
    k_four<<<NB * 128 / 256, 256, 0, stream>>>(pos, fB, four);
    k_z<<<dim3(4, 256), 256, 0, stream>>>(vis, four, img_W, img_b, pos_W, pos_b, z, z_hi, z_lo);
    k_router<<<NB / 4, 256, 0, stream>>>(z, grad, rW, rb, gate, eidx, cnt);
    k_offs<<<1, 64, 0, stream>>>(cnt, offs, cur);
    k_scatter<<<NB / 256, 256, 0, stream>>>(eidx, cur, list);
    k_exp1<<<dim3(NEXP * 8, NB / 128), 256, 0, stream>>>(z_hi, z_lo, w1t_h, w1t_l, eb1,
                                                         cnt, offs, list, H_hi, H_lo);
    k_exp2<<<dim3(NEXP * 2, NB / 128), 256, 0, stream>>>(H_hi, H_lo, w2et_h, w2et_l, eb2,
                                                         z, gate, cnt, offs, list, zf);
    k_gd1<<<NB / 16, 256, 0, stream>>>(zf, gdW1, gdb1, gdg, gdbeta, t_hi, t_lo);
    k_gd2_mfma<<<NPAD * 128 / 128, 256, 0, stream>>>(t_hi, t_lo, w2h, w2l, b2p, lib,
                                                     mu_out, th_out);
    k_heads<<<NB / 8, 256, 0, stream>>>(zf, apW1, apb1, apW2, apb2,
                                        fhW1, fhb1, fhW2, fhb2, func_out, align_out);
}